// Round 8
// baseline (1057.685 us; speedup 1.0000x reference)
//
#include <hip/hip_runtime.h>
#include <cstdint>
#include <cstddef>

typedef _Float16 half8 __attribute__((ext_vector_type(8)));
typedef _Float16 half4 __attribute__((ext_vector_type(4)));
typedef float floatx4 __attribute__((ext_vector_type(4)));

namespace {
constexpr int kB = 256, kT = 512, kIN = 48, kOUT = 48, kSEAS = 24, kH = 128;
constexpr int kW = kT - kIN + 1;           // 465 windows
constexpr int kWO = kT - kOUT - kIN + 1;   // 417
constexpr int kNB = kW * kB;               // 119040 rows
constexpr int kMBLK = kNB / 16;            // 7440 row-blocks of 16
constexpr float kLOG2E = 1.44269504088896340736f;
}

#if __has_builtin(__builtin_amdgcn_exp2f)
#define FEXP2(x) __builtin_amdgcn_exp2f(x)
#else
#define FEXP2(x) exp2f(x)
#endif
#if __has_builtin(__builtin_amdgcn_rcpf)
#define FRCP(x) __builtin_amdgcn_rcpf(x)
#else
#define FRCP(x) (1.0f / (x))
#endif

// LDS-only barrier: does NOT drain vmcnt -> global prefetches/stores stay in flight
#define LGKM_BARRIER() asm volatile("s_waitcnt lgkmcnt(0)\n\ts_barrier" ::: "memory")

__device__ __forceinline__ float fsig(float y) { return FRCP(1.0f + FEXP2(-y)); }
__device__ __forceinline__ float ftanh(float x) { return 2.0f * fsig(2.0f * kLOG2E * x) - 1.0f; }

// ---------------- transpose train (B,T) -> (T,B) ----------------
__global__ void k_transpose(const float* __restrict__ train, float* __restrict__ trainT) {
  int t = blockIdx.x, b = threadIdx.x;
  trainT[t * kB + b] = train[b * kT + t];
}

// ---------------- exponential smoothing scan (LDS ring) ----------------
__global__ void k_es(const float* __restrict__ trainT, const float* __restrict__ levp,
                     const float* __restrict__ seasp, const float* __restrict__ inits,
                     float* __restrict__ seas, float* __restrict__ levs) {
  __shared__ float ring[kSEAS][kB];
  int b = threadIdx.x;
  float lev_sm = fsig(levp[0] * kLOG2E);
  float seas_sm = fsig(seasp[0] * kLOG2E);
  float s00 = expf(inits[0]);
  for (int s = 0; s < kSEAS; ++s) {
    float v = expf(inits[s]);
    seas[s * kB + b] = v;
    if (s >= 1) ring[s - 1][b] = v;
  }
  ring[kSEAS - 1][b] = s00;
  seas[kSEAS * kB + b] = s00;
  float lev = trainT[b] * FRCP(s00);
  levs[b] = lev;
  int rk = 0;
  float x_nx = trainT[kB + b];
  float st_nx = ring[0][b];
  for (int k = 0; k < kT - 1; ++k) {
    float x = x_nx;
    float st = st_nx;
    if (k + 1 < kT - 1) x_nx = trainT[(k + 2) * kB + b];
    int rn = (rk + 1 == kSEAS) ? 0 : rk + 1;
    st_nx = ring[rn][b];
    float ln = lev_sm * (x * FRCP(st)) + (1.0f - lev_sm) * lev;
    float sn = seas_sm * (x * FRCP(ln)) + (1.0f - seas_sm) * st;
    ring[rk][b] = sn;
    seas[(k + kSEAS + 1) * kB + b] = sn;
    levs[(k + 1) * kB + b] = ln;
    lev = ln;
    rk = rn;
  }
  for (int j = 0; j < kOUT - kSEAS; ++j)
    seas[(kT + kSEAS + j) * kB + b] = seas[(kT + j) * kB + b];
}

// ---------------- window build: win_in (f16, padded K=64) ----------------
__global__ void k_win_in(const float* __restrict__ trainT, const float* __restrict__ seas,
                         const float* __restrict__ levs, _Float16* __restrict__ win) {
  int w = blockIdx.x;
  int tid = threadIdx.x;
#pragma unroll
  for (int i = 0; i < 16; ++i) {
    int o = i * 256 + tid;
    int b = o >> 3;
    int j0 = (o & 7) * 8;
    half8 h;
    if (j0 < kIN) {
      float rl = FRCP(levs[(kIN - 1 + w) * kB + b]);
#pragma unroll
      for (int jj = 0; jj < 8; ++jj) {
        int j = j0 + jj;
        int t = w + j;
        float v = (j < kIN) ? trainT[t * kB + b] * FRCP(seas[t * kB + b]) * rl : 0.0f;
        h[jj] = (_Float16)v;
      }
    } else {
#pragma unroll
      for (int jj = 0; jj < 8; ++jj) h[jj] = (_Float16)0.0f;
    }
    *(half8*)(win + ((size_t)(w * kB + b)) * 64 + j0) = h;
  }
}

// ---------------- window build: win_out == output 1 (fp32) ----------------
__global__ void k_win_out(const float* __restrict__ trainT, const float* __restrict__ seas,
                          const float* __restrict__ levs, float* __restrict__ out1) {
  int idx = blockIdx.x * 256 + threadIdx.x;
  if (idx >= kWO * kB * (kOUT / 4)) return;
  int row = idx / 12;
  int j0 = (idx - row * 12) * 4;
  int wo = row >> 8;
  int b = row & 255;
  float rl = FRCP(levs[(kIN - 1 + wo) * kB + b]);
  floatx4 v;
#pragma unroll
  for (int jj = 0; jj < 4; ++jj) {
    int t = kIN + wo + j0 + jj;
    v[jj] = trainT[t * kB + b] * FRCP(seas[t * kB + b]) * rl;
  }
  *(floatx4*)(out1 + (size_t)row * kOUT + j0) = v;
}

// ---------------- weight prep (single kernel, blockIdx.y = segment) ----------------
__device__ __forceinline__ void prep_bias_elem(const float* bih, const float* bhh, float* dst,
                                               int c) {
  int ct = c >> 4, n16 = c & 15, g = ct & 3, wv = ct >> 2;
  int row = g * 128 + wv * 16 + n16;
  float sc = (g == 2) ? 2.0f * kLOG2E : kLOG2E;
  dst[c] = (bih[row] + bhh[row]) * sc;
}

__device__ __forceinline__ void prep_frag_elem(const float* Wsrc, _Float16* dst, int KB, int Kreal,
                                               int srcld, int perm, int idx) {
  int jj = idx & 7;
  int lane = (idx >> 3) & 63;
  int kb = (idx >> 9) % KB;
  int ct = idx / (KB * 512);
  int n16 = lane & 15;
  int k = kb * 32 + ((lane >> 4) << 3) + jj;
  int row;
  float sc;
  if (perm) {
    int g = ct & 3, wv = ct >> 2;
    row = g * 128 + wv * 16 + n16;
    sc = (g == 2) ? 2.0f * kLOG2E : kLOG2E;
  } else {
    row = ct * 16 + n16;
    sc = 1.0f;
  }
  float v = (k < Kreal) ? Wsrc[row * srcld + k] * sc : 0.0f;
  dst[idx] = (_Float16)v;
}

struct PrepArgs {
  const float* bih[4];
  const float* bhh[4];
  float* biasp[4];
  const float* wih[4];
  _Float16* wihf[4];
  const float* whh[4];
  _Float16* whhf[4];
  const float* nlw;
  _Float16* nlf;
  const float* scw;
  _Float16* scf;
};

__global__ void k_prep_all(PrepArgs a) {
  int seg = blockIdx.y;
  int idx = blockIdx.x * 256 + threadIdx.x;
  if (seg < 4) {
    if (idx < 512) prep_bias_elem(a.bih[seg], a.bhh[seg], a.biasp[seg], idx);
  } else if (seg == 4) {
    if (idx < 32 * 2 * 512) prep_frag_elem(a.wih[0], a.wihf[0], 2, 48, 48, 1, idx);
  } else if (seg < 8) {
    int c = seg - 4;
    if (idx < 32 * 4 * 512) prep_frag_elem(a.wih[c], a.wihf[c], 4, 128, 128, 1, idx);
  } else if (seg < 12) {
    int c = seg - 8;
    if (idx < 32 * 4 * 512) prep_frag_elem(a.whh[c], a.whhf[c], 4, 128, 128, 1, idx);
  } else if (seg == 12) {
    if (idx < 8 * 4 * 512) prep_frag_elem(a.nlw, a.nlf, 4, 128, 128, 0, idx);
  } else {
    if (idx < 3 * 4 * 512) prep_frag_elem(a.scw, a.scf, 4, 128, 128, 0, idx);
  }
}

__global__ void k_zero_prog(int* prog) {
  prog[threadIdx.x] = 0;  // 256 ints: [0,192) used
}

// ---------------- generic MFMA GEMM (nl: MODE1, sc: MODE2) ----------------
template <int NT, int KB, int MODE>
__global__ __launch_bounds__(512) void k_gemm(const _Float16* __restrict__ A,
                                              const _Float16* __restrict__ A2, int Khalfs,
                                              const _Float16* __restrict__ Bfr,
                                              const float* __restrict__ bias,
                                              _Float16* __restrict__ outh,
                                              float* __restrict__ outf,
                                              float* __restrict__ outf2) {
  __shared__ _Float16 bsh[NT * KB * 512];
  int tid = threadIdx.x;
  {
    const uint4* src = (const uint4*)Bfr;
    uint4* dst = (uint4*)bsh;
    for (int i = tid; i < NT * KB * 64; i += 512) dst[i] = src[i];
  }
  __syncthreads();
  int wv = tid >> 6, lane = tid & 63;
  int mblk = blockIdx.x * 8 + wv;
  if (mblk >= kMBLK) return;
  int m = lane & 15, kq = lane >> 4;
  const _Float16* arow = A + (size_t)(mblk * 16 + m) * Khalfs + kq * 8;
  half8 af[KB];
#pragma unroll
  for (int kb = 0; kb < KB; ++kb) af[kb] = *(const half8*)(arow + kb * 32);
  if constexpr (MODE == 1) {
    const _Float16* arow2 = A2 + (size_t)(mblk * 16 + m) * Khalfs + kq * 8;
#pragma unroll
    for (int kb = 0; kb < KB; ++kb) {
      half8 a2 = *(const half8*)(arow2 + kb * 32);
      af[kb] += a2;
    }
  }
#pragma unroll
  for (int t0 = 0; t0 < NT; t0 += 2) {
    float b0 = bias[t0 * 16 + m];
    floatx4 acc0 = {b0, b0, b0, b0};
    floatx4 acc1 = {0.f, 0.f, 0.f, 0.f};
    if (t0 + 1 < NT) {
      float b1 = bias[(t0 + 1) * 16 + m];
      acc1 = (floatx4){b1, b1, b1, b1};
    }
#pragma unroll
    for (int kb = 0; kb < KB; ++kb) {
      half8 bf0 = *(const half8*)(&bsh[((t0 * KB + kb) * 64 + lane) * 8]);
      acc0 = __builtin_amdgcn_mfma_f32_16x16x32_f16(af[kb], bf0, acc0, 0, 0, 0);
      if (t0 + 1 < NT) {
        half8 bf1 = *(const half8*)(&bsh[(((t0 + 1) * KB + kb) * 64 + lane) * 8]);
        acc1 = __builtin_amdgcn_mfma_f32_16x16x32_f16(af[kb], bf1, acc1, 0, 0, 0);
      }
    }
    if constexpr (MODE == 1) {
#pragma unroll
      for (int r = 0; r < 4; ++r) {
        int row = mblk * 16 + kq * 4 + r;
        outh[(size_t)row * kH + t0 * 16 + m] = (_Float16)ftanh(acc0[r]);
        if (t0 + 1 < NT) outh[(size_t)row * kH + (t0 + 1) * 16 + m] = (_Float16)ftanh(acc1[r]);
      }
    } else {
#pragma unroll
      for (int r = 0; r < 4; ++r) {
        int row = mblk * 16 + kq * 4 + r;
        float v0 = acc0[r];
        outf[(size_t)row * kOUT + t0 * 16 + m] = v0;
        if (row < kWO * kB) outf2[(size_t)row * kOUT + t0 * 16 + m] = v0;
        if (t0 + 1 < NT) {
          float v1 = acc1[r];
          outf[(size_t)row * kOUT + (t0 + 1) * 16 + m] = v1;
          if (row < kWO * kB) outf2[(size_t)row * kOUT + (t0 + 1) * 16 + m] = v1;
        }
      }
    }
  }
}

// ---------------- fused 4-cell streaming LSTM, TWO chains per WG ----------------
// 120 WGs: cell0=wg[0,8) d=1; cell1=[8,24) d=2; cell2=[24,56) d=4; cell3=[56,120) d=8.
// WG handles chains (kd, ib=2i) and (kd, ib=2i+1) interleaved in one instruction
// stream so chain A's trans-pipe gate math overlaps chain B's MFMAs (and vice versa).
// Producers/consumers of an ib-pair stay on the same XCD (all base offsets === 0 mod 8).
// Sync: RELAXED polls + one acquire fence per newly-observed release quantum (R4).
struct FArgs {
  const _Float16* win;
  const _Float16* wihf[4];
  const _Float16* whhf[4];
  const float* biasp[4];
  _Float16* H[4];
  int* prog;
};

__device__ __forceinline__ void wait2(int* pA, int* pB, int need, int& fenced, int* obs_sh) {
  if (need <= fenced) return;  // uniform: no divergence hazard
  if (threadIdx.x == 0) {
    int vA, vB;
    while ((vA = __hip_atomic_load(pA, __ATOMIC_RELAXED, __HIP_MEMORY_SCOPE_AGENT)) < need)
      __builtin_amdgcn_s_sleep(16);
    while ((vB = __hip_atomic_load(pB, __ATOMIC_RELAXED, __HIP_MEMORY_SCOPE_AGENT)) < need)
      __builtin_amdgcn_s_sleep(16);
    *obs_sh = vA < vB ? vA : vB;
  }
  __syncthreads();
  int v = *obs_sh;
  __builtin_amdgcn_fence(__ATOMIC_ACQUIRE, "agent");  // single buffer_inv
  fenced = v;
}

// Dual-chain LSTM loop. KXB: X K-blocks (2 for cell0 win, 4 for H inputs).
// XPF: register double-buffer prefetch of X (cell0 only; others load JIT from L2-hot H).
template <int KXB, bool POLL, bool REL, bool XPF>
__device__ __forceinline__ void floop2(const _Float16* __restrict__ Xsrc,
                                       const _Float16* __restrict__ wihp,
                                       const _Float16* __restrict__ whhp,
                                       const float* __restrict__ bp,
                                       _Float16* __restrict__ Hout, int* progInA, int* progInB,
                                       int sprev, int* progOutA, int* progOutB, int d, int kd,
                                       int ibA, int ibB, _Float16 (*hbuf)[2][2048],
                                       int* obs_sh) {
  int tid = threadIdx.x;
  int wv = tid >> 6, lane = tid & 63, m = lane & 15, kq = lane >> 4;
  half8 wxf[4][KXB], whf[4][4];
#pragma unroll
  for (int g = 0; g < 4; ++g) {
#pragma unroll
    for (int kb = 0; kb < KXB; ++kb)
      wxf[g][kb] = *(const half8*)(wihp + ((((wv * 4 + g) * KXB + kb) * 64 + lane) * 8));
#pragma unroll
    for (int kb = 0; kb < 4; ++kb)
      whf[g][kb] = *(const half8*)(whhp + ((((wv * 4 + g) * 4 + kb) * 64 + lane) * 8));
  }
  float bg[4];
#pragma unroll
  for (int g = 0; g < 4; ++g) bg[g] = bp[(wv * 4 + g) * 16 + m];
  float ccA[4] = {0.f, 0.f, 0.f, 0.f}, ccB[4] = {0.f, 0.f, 0.f, 0.f};
  int nsteps = (kW - kd + d - 1) / d;
  const int xstride = KXB * 32;
  int fenced = 0;
  half8 hxcA[KXB], hxcB[KXB], hxnA[KXB], hxnB[KXB];
  if (XPF) {
    const _Float16* xrA = Xsrc + (size_t)(kd * kB + ibA * 16 + m) * xstride + kq * 8;
    const _Float16* xrB = Xsrc + (size_t)(kd * kB + ibB * 16 + m) * xstride + kq * 8;
#pragma unroll
    for (int kb = 0; kb < KXB; ++kb) {
      hxcA[kb] = *(const half8*)(xrA + kb * 32);
      hxcB[kb] = *(const half8*)(xrB + kb * 32);
    }
  }
  for (int j = 0; j < nsteps; ++j) {
    int ph = j & 1;
    int wt = j * d + kd;
    if (POLL) {
      int kdp = wt & ((1 << sprev) - 1), need = (wt >> sprev) + 1;
      wait2(progInA + kdp, progInB + kdp, need, fenced, obs_sh);
    }
    if (!XPF) {  // JIT loads from producer H (L2-hot)
      const _Float16* xrA = Xsrc + (size_t)(wt * kB + ibA * 16 + m) * xstride + kq * 8;
      const _Float16* xrB = Xsrc + (size_t)(wt * kB + ibB * 16 + m) * xstride + kq * 8;
#pragma unroll
      for (int kb = 0; kb < KXB; ++kb) {
        hxcA[kb] = *(const half8*)(xrA + kb * 32);
        hxcB[kb] = *(const half8*)(xrB + kb * 32);
      }
    } else if (j + 1 < nsteps) {  // prefetch next step
      int wtn = wt + d;
      const _Float16* xrA = Xsrc + (size_t)(wtn * kB + ibA * 16 + m) * xstride + kq * 8;
      const _Float16* xrB = Xsrc + (size_t)(wtn * kB + ibB * 16 + m) * xstride + kq * 8;
#pragma unroll
      for (int kb = 0; kb < KXB; ++kb) {
        hxnA[kb] = *(const half8*)(xrA + kb * 32);
        hxnB[kb] = *(const half8*)(xrB + kb * 32);
      }
    }
    // LDS h reads for both chains (prev step's h)
    half8 aA[4], aB[4];
    if (j > 0) {
#pragma unroll
      for (int kb = 0; kb < 4; ++kb) {
        int gran = (kb * 4 + kq) ^ m;
        aA[kb] = *(const half8*)(&hbuf[0][ph ^ 1][m * 128 + gran * 8]);
        aB[kb] = *(const half8*)(&hbuf[1][ph ^ 1][m * 128 + gran * 8]);
      }
    }
    floatx4 accA[4], accB[4];
#pragma unroll
    for (int g = 0; g < 4; ++g) {
      accA[g] = (floatx4){bg[g], bg[g], bg[g], bg[g]};
      accB[g] = (floatx4){bg[g], bg[g], bg[g], bg[g]};
    }
    // chain A MFMAs
#pragma unroll
    for (int kb = 0; kb < KXB; ++kb)
#pragma unroll
      for (int g = 0; g < 4; ++g)
        accA[g] = __builtin_amdgcn_mfma_f32_16x16x32_f16(hxcA[kb], wxf[g][kb], accA[g], 0, 0, 0);
    if (j > 0) {
#pragma unroll
      for (int kb = 0; kb < 4; ++kb)
#pragma unroll
        for (int g = 0; g < 4; ++g)
          accA[g] = __builtin_amdgcn_mfma_f32_16x16x32_f16(aA[kb], whf[g][kb], accA[g], 0, 0, 0);
    }
    // chain B MFMAs (fill matrix pipe while A's gate math runs)
#pragma unroll
    for (int kb = 0; kb < KXB; ++kb)
#pragma unroll
      for (int g = 0; g < 4; ++g)
        accB[g] = __builtin_amdgcn_mfma_f32_16x16x32_f16(hxcB[kb], wxf[g][kb], accB[g], 0, 0, 0);
    if (j > 0) {
#pragma unroll
      for (int kb = 0; kb < 4; ++kb)
#pragma unroll
        for (int g = 0; g < 4; ++g)
          accB[g] = __builtin_amdgcn_mfma_f32_16x16x32_f16(aB[kb], whf[g][kb], accB[g], 0, 0, 0);
    }
    // gate math A then B (8 trans/h): trans pipe overlaps B's in-flight MFMAs
    _Float16 hvA[4], hvB[4];
#pragma unroll
    for (int r = 0; r < 4; ++r) {
      float ea = FEXP2(-accA[0][r]);
      float ef = FEXP2(-accA[1][r]);
      float eb = FEXP2(-accA[2][r]);
      float eo = FEXP2(-accA[3][r]);
      float fv = FRCP(1.0f + ef);
      float it = (1.0f - eb) * FRCP((1.0f + ea) * (1.0f + eb));
      ccA[r] = fv * ccA[r] + it;
      float ed = FEXP2(ccA[r] * (-2.0f * kLOG2E));
      hvA[r] = (_Float16)((1.0f - ed) * FRCP((1.0f + eo) * (1.0f + ed)));
    }
#pragma unroll
    for (int r = 0; r < 4; ++r) {
      float ea = FEXP2(-accB[0][r]);
      float ef = FEXP2(-accB[1][r]);
      float eb = FEXP2(-accB[2][r]);
      float eo = FEXP2(-accB[3][r]);
      float fv = FRCP(1.0f + ef);
      float it = (1.0f - eb) * FRCP((1.0f + ea) * (1.0f + eb));
      ccB[r] = fv * ccB[r] + it;
      float ed = FEXP2(ccB[r] * (-2.0f * kLOG2E));
      hvB[r] = (_Float16)((1.0f - ed) * FRCP((1.0f + eo) * (1.0f + ed)));
    }
#pragma unroll
    for (int r = 0; r < 4; ++r) {
      int brow = kq * 4 + r;
      int hu = wv * 16 + m;
      int gran = (hu >> 3) ^ brow;
      hbuf[0][ph][brow * 128 + gran * 8 + (hu & 7)] = hvA[r];
      hbuf[1][ph][brow * 128 + gran * 8 + (hu & 7)] = hvB[r];
    }
    LGKM_BARRIER();  // LDS-only: global prefetch + H stores stay in flight
    {  // direct register->global stores (drain lazily)
      int hu = wv * 16 + m;
      size_t rbA = (size_t)(wt * kB + ibA * 16 + kq * 4);
      size_t rbB = (size_t)(wt * kB + ibB * 16 + kq * 4);
#pragma unroll
      for (int r = 0; r < 4; ++r) {
        Hout[(rbA + r) * kH + hu] = hvA[r];
        Hout[(rbB + r) * kH + hu] = hvB[r];
      }
    }
    if (REL && (((j & 7) == 7) || (j + 1 == nsteps))) {
      __syncthreads();  // full drain (vmcnt0): H stores visible before release
      if (tid == 0) {
        __hip_atomic_store(progOutA, j + 1, __ATOMIC_RELEASE, __HIP_MEMORY_SCOPE_AGENT);
        __hip_atomic_store(progOutB, j + 1, __ATOMIC_RELEASE, __HIP_MEMORY_SCOPE_AGENT);
      }
    }
    if (XPF) {
#pragma unroll
      for (int kb = 0; kb < KXB; ++kb) {
        hxcA[kb] = hxnA[kb];
        hxcB[kb] = hxnB[kb];
      }
    }
  }
}

__global__ __launch_bounds__(512) void k_fused(FArgs a) {
  __shared__ _Float16 hbuf[2][2][2048];
  __shared__ int obs_sh;
  int w = blockIdx.x;
  int cell, d, kd, ip;
  if (w < 8) {
    cell = 0; d = 1; kd = 0; ip = w;
  } else if (w < 24) {
    cell = 1; d = 2; int idx = w - 8; kd = idx >> 3; ip = idx & 7;
  } else if (w < 56) {
    cell = 2; d = 4; int idx = w - 24; kd = idx >> 3; ip = idx & 7;
  } else {
    cell = 3; d = 8; int idx = w - 56; kd = idx >> 3; ip = idx & 7;
  }
  int ibA = ip * 2, ibB = ip * 2 + 1;
  const _Float16* Xsrc = (cell == 0) ? a.win : a.H[cell - 1];
  _Float16* Hout = a.H[cell];
  int* progOutA = a.prog + (cell * 16 + ibA) * 4 + kd;
  int* progOutB = a.prog + (cell * 16 + ibB) * 4 + kd;
  int* progInA = (cell > 0) ? a.prog + ((cell - 1) * 16 + ibA) * 4 : nullptr;
  int* progInB = (cell > 0) ? a.prog + ((cell - 1) * 16 + ibB) * 4 : nullptr;
  int sprev = (cell == 2) ? 1 : ((cell == 3) ? 2 : 0);
  if (cell == 0)
    floop2<2, false, true, true>(Xsrc, a.wihf[0], a.whhf[0], a.biasp[0], Hout, nullptr, nullptr,
                                 0, progOutA, progOutB, d, kd, ibA, ibB, hbuf, &obs_sh);
  else if (cell < 3)
    floop2<4, true, true, false>(Xsrc, a.wihf[cell], a.whhf[cell], a.biasp[cell], Hout, progInA,
                                 progInB, sprev, progOutA, progOutB, d, kd, ibA, ibB, hbuf,
                                 &obs_sh);
  else
    floop2<4, true, false, false>(Xsrc, a.wihf[3], a.whhf[3], a.biasp[3], Hout, progInA,
                                  progInB, sprev, progOutA, progOutB, d, kd, ibA, ibB, hbuf,
                                  &obs_sh);
}

// ---------------- tail: outputs 2, 4, 5 ----------------
__global__ void k_tail(const float* __restrict__ out3, const float* __restrict__ val,
                       const float* __restrict__ seas, const float* __restrict__ levs,
                       float* __restrict__ out2, float* __restrict__ out4,
                       float* __restrict__ out5) {
  int idx = blockIdx.x * 256 + threadIdx.x;
  int b = idx / kOUT, j = idx % kOUT;
  float s = seas[(kT + j) * kB + b];
  float L = levs[(kT - 1) * kB + b];
  float net = out3[(size_t)(kW - 1) * kB * kOUT + idx];
  float hp = net * s * L;
  out2[idx] = hp > 0.0f ? hp : 0.0f;
  float v = val[idx];
  out4[idx] = v;
  out5[idx] = v / s / L;
}

extern "C" void kernel_launch(void* const* d_in, const int* in_sizes, int n_in, void* d_out,
                              int out_size, void* d_ws, size_t ws_size, hipStream_t stream) {
  const float* train = (const float*)d_in[0];
  const float* val = (const float*)d_in[1];
  const float* levp = (const float*)d_in[3];
  const float* seasp = (const float*)d_in[4];
  const float* inits = (const float*)d_in[5];
  const float* w_ih[4] = {(const float*)d_in[6], (const float*)d_in[10], (const float*)d_in[14],
                          (const float*)d_in[18]};
  const float* w_hh[4] = {(const float*)d_in[7], (const float*)d_in[11], (const float*)d_in[15],
                          (const float*)d_in[19]};
  const float* b_ih[4] = {(const float*)d_in[8], (const float*)d_in[12], (const float*)d_in[16],
                          (const float*)d_in[20]};
  const float* b_hh[4] = {(const float*)d_in[9], (const float*)d_in[13], (const float*)d_in[17],
                          (const float*)d_in[21]};
  const float* nl_w = (const float*)d_in[22];
  const float* nl_b = (const float*)d_in[23];
  const float* sc_w = (const float*)d_in[24];
  const float* sc_b = (const float*)d_in[25];

  char* wsb = (char*)d_ws;
  size_t off = 0;
  auto alloc = [&](size_t bytes) -> void* {
    void* p = wsb + off;
    off = (off + bytes + 255) & ~(size_t)255;
    return p;
  };
  float* trainT = (float*)alloc((size_t)kT * kB * 4);
  float* seas = (float*)alloc((size_t)560 * kB * 4);
  float* levs = (float*)alloc((size_t)kT * kB * 4);
  _Float16* win = (_Float16*)alloc((size_t)kNB * 64 * 2);
  _Float16* Hc[4];
  for (int c = 0; c < 4; ++c) Hc[c] = (_Float16*)alloc((size_t)kNB * kH * 2);
  _Float16* U = (_Float16*)alloc((size_t)kNB * kH * 2);
  float* biasp[4];
  for (int c = 0; c < 4; ++c) biasp[c] = (float*)alloc(512 * 4);
  _Float16* wihf[4];
  wihf[0] = (_Float16*)alloc((size_t)32 * 2 * 512 * 2);
  for (int c = 1; c < 4; ++c) wihf[c] = (_Float16*)alloc((size_t)32 * 4 * 512 * 2);
  _Float16* whhf[4];
  for (int c = 0; c < 4; ++c) whhf[c] = (_Float16*)alloc((size_t)32 * 4 * 512 * 2);
  _Float16* nlf = (_Float16*)alloc((size_t)8 * 4 * 512 * 2);
  _Float16* scf = (_Float16*)alloc((size_t)3 * 4 * 512 * 2);
  int* prog = (int*)alloc(256 * 4);

  float* out0 = (float*)d_out;
  float* out1 = out0 + (size_t)kWO * kB * kOUT;
  float* out2 = out1 + (size_t)kWO * kB * kOUT;
  float* out3 = out2 + (size_t)kB * kOUT;
  float* out4 = out3 + (size_t)kW * kB * kOUT;
  float* out5 = out4 + (size_t)kB * kOUT;

  k_transpose<<<kT, kB, 0, stream>>>(train, trainT);
  k_es<<<1, kB, 0, stream>>>(trainT, levp, seasp, inits, seas, levs);
  k_win_in<<<kW, kB, 0, stream>>>(trainT, seas, levs, win);
  k_win_out<<<(kWO * kB * 12 + 255) / 256, 256, 0, stream>>>(trainT, seas, levs, out1);

  PrepArgs pa;
  for (int c = 0; c < 4; ++c) {
    pa.bih[c] = b_ih[c]; pa.bhh[c] = b_hh[c]; pa.biasp[c] = biasp[c];
    pa.wih[c] = w_ih[c]; pa.wihf[c] = wihf[c];
    pa.whh[c] = w_hh[c]; pa.whhf[c] = whhf[c];
  }
  pa.nlw = nl_w; pa.nlf = nlf; pa.scw = sc_w; pa.scf = scf;
  k_prep_all<<<dim3(256, 14), 256, 0, stream>>>(pa);
  k_zero_prog<<<1, 256, 0, stream>>>(prog);

  FArgs fa;
  fa.win = win;
  for (int c = 0; c < 4; ++c) {
    fa.wihf[c] = wihf[c]; fa.whhf[c] = whhf[c]; fa.biasp[c] = biasp[c]; fa.H[c] = Hc[c];
  }
  fa.prog = prog;
  void* kp[1] = {(void*)&fa};
  hipLaunchCooperativeKernel((void*)k_fused, dim3(120), dim3(512), kp, 0, stream);

  const int GG = kMBLK / 8;  // 930
  // nl: A = H3 + H1 (residual), tanh -> U
  k_gemm<8, 4, 1><<<GG, 512, 0, stream>>>(Hc[3], Hc[1], 128, nlf, nl_b, U, nullptr, nullptr);
  // sc: f32 out -> net_out_all (out3) + network_pred (out0)
  k_gemm<3, 4, 2><<<GG, 512, 0, stream>>>(U, nullptr, 128, scf, sc_b, nullptr, out3, out0);
  k_tail<<<48, 256, 0, stream>>>(out3, val, seas, levs, out2, out4, out5);
}

// Round 9
// 737.855 us; speedup vs baseline: 1.4335x; 1.4335x over previous
//
#include <hip/hip_runtime.h>
#include <cstdint>
#include <cstddef>

typedef _Float16 half8 __attribute__((ext_vector_type(8)));
typedef _Float16 half4 __attribute__((ext_vector_type(4)));
typedef float floatx4 __attribute__((ext_vector_type(4)));

namespace {
constexpr int kB = 256, kT = 512, kIN = 48, kOUT = 48, kSEAS = 24, kH = 128;
constexpr int kW = kT - kIN + 1;           // 465 windows
constexpr int kWO = kT - kOUT - kIN + 1;   // 417
constexpr int kNB = kW * kB;               // 119040 rows
constexpr int kMBLK = kNB / 16;            // 7440 row-blocks of 16
constexpr float kLOG2E = 1.44269504088896340736f;
}

#if __has_builtin(__builtin_amdgcn_exp2f)
#define FEXP2(x) __builtin_amdgcn_exp2f(x)
#else
#define FEXP2(x) exp2f(x)
#endif
#if __has_builtin(__builtin_amdgcn_rcpf)
#define FRCP(x) __builtin_amdgcn_rcpf(x)
#else
#define FRCP(x) (1.0f / (x))
#endif

// LDS-only barrier: does NOT drain vmcnt -> global prefetches/stores stay in flight
#define LGKM_BARRIER() asm volatile("s_waitcnt lgkmcnt(0)\n\ts_barrier" ::: "memory")

__device__ __forceinline__ float fsig(float y) { return FRCP(1.0f + FEXP2(-y)); }
__device__ __forceinline__ float ftanh(float x) { return 2.0f * fsig(2.0f * kLOG2E * x) - 1.0f; }

// ---------------- transpose train (B,T) -> (T,B) ----------------
__global__ void k_transpose(const float* __restrict__ train, float* __restrict__ trainT) {
  int t = blockIdx.x, b = threadIdx.x;
  trainT[t * kB + b] = train[b * kT + t];
}

// ---------------- exponential smoothing scan (LDS ring) ----------------
__global__ void k_es(const float* __restrict__ trainT, const float* __restrict__ levp,
                     const float* __restrict__ seasp, const float* __restrict__ inits,
                     float* __restrict__ seas, float* __restrict__ levs) {
  __shared__ float ring[kSEAS][kB];
  int b = threadIdx.x;
  float lev_sm = fsig(levp[0] * kLOG2E);
  float seas_sm = fsig(seasp[0] * kLOG2E);
  float s00 = expf(inits[0]);
  for (int s = 0; s < kSEAS; ++s) {
    float v = expf(inits[s]);
    seas[s * kB + b] = v;
    if (s >= 1) ring[s - 1][b] = v;
  }
  ring[kSEAS - 1][b] = s00;
  seas[kSEAS * kB + b] = s00;
  float lev = trainT[b] * FRCP(s00);
  levs[b] = lev;
  int rk = 0;
  float x_nx = trainT[kB + b];
  float st_nx = ring[0][b];
  for (int k = 0; k < kT - 1; ++k) {
    float x = x_nx;
    float st = st_nx;
    if (k + 1 < kT - 1) x_nx = trainT[(k + 2) * kB + b];
    int rn = (rk + 1 == kSEAS) ? 0 : rk + 1;
    st_nx = ring[rn][b];
    float ln = lev_sm * (x * FRCP(st)) + (1.0f - lev_sm) * lev;
    float sn = seas_sm * (x * FRCP(ln)) + (1.0f - seas_sm) * st;
    ring[rk][b] = sn;
    seas[(k + kSEAS + 1) * kB + b] = sn;
    levs[(k + 1) * kB + b] = ln;
    lev = ln;
    rk = rn;
  }
  for (int j = 0; j < kOUT - kSEAS; ++j)
    seas[(kT + kSEAS + j) * kB + b] = seas[(kT + j) * kB + b];
}

// ---------------- window build: win_in (f16, padded K=64) ----------------
__global__ void k_win_in(const float* __restrict__ trainT, const float* __restrict__ seas,
                         const float* __restrict__ levs, _Float16* __restrict__ win) {
  int w = blockIdx.x;
  int tid = threadIdx.x;
#pragma unroll
  for (int i = 0; i < 16; ++i) {
    int o = i * 256 + tid;
    int b = o >> 3;
    int j0 = (o & 7) * 8;
    half8 h;
    if (j0 < kIN) {
      float rl = FRCP(levs[(kIN - 1 + w) * kB + b]);
#pragma unroll
      for (int jj = 0; jj < 8; ++jj) {
        int j = j0 + jj;
        int t = w + j;
        float v = (j < kIN) ? trainT[t * kB + b] * FRCP(seas[t * kB + b]) * rl : 0.0f;
        h[jj] = (_Float16)v;
      }
    } else {
#pragma unroll
      for (int jj = 0; jj < 8; ++jj) h[jj] = (_Float16)0.0f;
    }
    *(half8*)(win + ((size_t)(w * kB + b)) * 64 + j0) = h;
  }
}

// ---------------- window build: win_out == output 1 (fp32) ----------------
__global__ void k_win_out(const float* __restrict__ trainT, const float* __restrict__ seas,
                          const float* __restrict__ levs, float* __restrict__ out1) {
  int idx = blockIdx.x * 256 + threadIdx.x;
  if (idx >= kWO * kB * (kOUT / 4)) return;
  int row = idx / 12;
  int j0 = (idx - row * 12) * 4;
  int wo = row >> 8;
  int b = row & 255;
  float rl = FRCP(levs[(kIN - 1 + wo) * kB + b]);
  floatx4 v;
#pragma unroll
  for (int jj = 0; jj < 4; ++jj) {
    int t = kIN + wo + j0 + jj;
    v[jj] = trainT[t * kB + b] * FRCP(seas[t * kB + b]) * rl;
  }
  *(floatx4*)(out1 + (size_t)row * kOUT + j0) = v;
}

// ---------------- weight prep (single kernel, blockIdx.y = segment) ----------------
__device__ __forceinline__ void prep_bias_elem(const float* bih, const float* bhh, float* dst,
                                               int c) {
  int ct = c >> 4, n16 = c & 15, g = ct & 3, wv = ct >> 2;
  int row = g * 128 + wv * 16 + n16;
  float sc = (g == 2) ? 2.0f * kLOG2E : kLOG2E;
  dst[c] = (bih[row] + bhh[row]) * sc;
}

__device__ __forceinline__ void prep_frag_elem(const float* Wsrc, _Float16* dst, int KB, int Kreal,
                                               int srcld, int perm, int idx) {
  int jj = idx & 7;
  int lane = (idx >> 3) & 63;
  int kb = (idx >> 9) % KB;
  int ct = idx / (KB * 512);
  int n16 = lane & 15;
  int k = kb * 32 + ((lane >> 4) << 3) + jj;
  int row;
  float sc;
  if (perm) {
    int g = ct & 3, wv = ct >> 2;
    row = g * 128 + wv * 16 + n16;
    sc = (g == 2) ? 2.0f * kLOG2E : kLOG2E;
  } else {
    row = ct * 16 + n16;
    sc = 1.0f;
  }
  float v = (k < Kreal) ? Wsrc[row * srcld + k] * sc : 0.0f;
  dst[idx] = (_Float16)v;
}

struct PrepArgs {
  const float* bih[4];
  const float* bhh[4];
  float* biasp[4];
  const float* wih[4];
  _Float16* wihf[4];
  const float* whh[4];
  _Float16* whhf[4];
  const float* nlw;
  _Float16* nlf;
  const float* scw;
  _Float16* scf;
};

__global__ void k_prep_all(PrepArgs a) {
  int seg = blockIdx.y;
  int idx = blockIdx.x * 256 + threadIdx.x;
  if (seg < 4) {
    if (idx < 512) prep_bias_elem(a.bih[seg], a.bhh[seg], a.biasp[seg], idx);
  } else if (seg == 4) {
    if (idx < 32 * 2 * 512) prep_frag_elem(a.wih[0], a.wihf[0], 2, 48, 48, 1, idx);
  } else if (seg < 8) {
    int c = seg - 4;
    if (idx < 32 * 4 * 512) prep_frag_elem(a.wih[c], a.wihf[c], 4, 128, 128, 1, idx);
  } else if (seg < 12) {
    int c = seg - 8;
    if (idx < 32 * 4 * 512) prep_frag_elem(a.whh[c], a.whhf[c], 4, 128, 128, 1, idx);
  } else if (seg == 12) {
    if (idx < 8 * 4 * 512) prep_frag_elem(a.nlw, a.nlf, 4, 128, 128, 0, idx);
  } else {
    if (idx < 3 * 4 * 512) prep_frag_elem(a.scw, a.scf, 4, 128, 128, 0, idx);
  }
}

__global__ void k_zero_prog(int* prog) {
  prog[threadIdx.x] = 0;  // 256 ints: [0,192) used
}

// ---------------- generic MFMA GEMM (nl: MODE1, sc: MODE2) ----------------
template <int NT, int KB, int MODE>
__global__ __launch_bounds__(512) void k_gemm(const _Float16* __restrict__ A,
                                              const _Float16* __restrict__ A2, int Khalfs,
                                              const _Float16* __restrict__ Bfr,
                                              const float* __restrict__ bias,
                                              _Float16* __restrict__ outh,
                                              float* __restrict__ outf,
                                              float* __restrict__ outf2) {
  __shared__ _Float16 bsh[NT * KB * 512];
  int tid = threadIdx.x;
  {
    const uint4* src = (const uint4*)Bfr;
    uint4* dst = (uint4*)bsh;
    for (int i = tid; i < NT * KB * 64; i += 512) dst[i] = src[i];
  }
  __syncthreads();
  int wv = tid >> 6, lane = tid & 63;
  int mblk = blockIdx.x * 8 + wv;
  if (mblk >= kMBLK) return;
  int m = lane & 15, kq = lane >> 4;
  const _Float16* arow = A + (size_t)(mblk * 16 + m) * Khalfs + kq * 8;
  half8 af[KB];
#pragma unroll
  for (int kb = 0; kb < KB; ++kb) af[kb] = *(const half8*)(arow + kb * 32);
  if constexpr (MODE == 1) {
    const _Float16* arow2 = A2 + (size_t)(mblk * 16 + m) * Khalfs + kq * 8;
#pragma unroll
    for (int kb = 0; kb < KB; ++kb) {
      half8 a2 = *(const half8*)(arow2 + kb * 32);
      af[kb] += a2;
    }
  }
#pragma unroll
  for (int t0 = 0; t0 < NT; t0 += 2) {
    float b0 = bias[t0 * 16 + m];
    floatx4 acc0 = {b0, b0, b0, b0};
    floatx4 acc1 = {0.f, 0.f, 0.f, 0.f};
    if (t0 + 1 < NT) {
      float b1 = bias[(t0 + 1) * 16 + m];
      acc1 = (floatx4){b1, b1, b1, b1};
    }
#pragma unroll
    for (int kb = 0; kb < KB; ++kb) {
      half8 bf0 = *(const half8*)(&bsh[((t0 * KB + kb) * 64 + lane) * 8]);
      acc0 = __builtin_amdgcn_mfma_f32_16x16x32_f16(af[kb], bf0, acc0, 0, 0, 0);
      if (t0 + 1 < NT) {
        half8 bf1 = *(const half8*)(&bsh[(((t0 + 1) * KB + kb) * 64 + lane) * 8]);
        acc1 = __builtin_amdgcn_mfma_f32_16x16x32_f16(af[kb], bf1, acc1, 0, 0, 0);
      }
    }
    if constexpr (MODE == 1) {
#pragma unroll
      for (int r = 0; r < 4; ++r) {
        int row = mblk * 16 + kq * 4 + r;
        outh[(size_t)row * kH + t0 * 16 + m] = (_Float16)ftanh(acc0[r]);
        if (t0 + 1 < NT) outh[(size_t)row * kH + (t0 + 1) * 16 + m] = (_Float16)ftanh(acc1[r]);
      }
    } else {
#pragma unroll
      for (int r = 0; r < 4; ++r) {
        int row = mblk * 16 + kq * 4 + r;
        float v0 = acc0[r];
        outf[(size_t)row * kOUT + t0 * 16 + m] = v0;
        if (row < kWO * kB) outf2[(size_t)row * kOUT + t0 * 16 + m] = v0;
        if (t0 + 1 < NT) {
          float v1 = acc1[r];
          outf[(size_t)row * kOUT + (t0 + 1) * 16 + m] = v1;
          if (row < kWO * kB) outf2[(size_t)row * kOUT + (t0 + 1) * 16 + m] = v1;
        }
      }
    }
  }
}

// ---------------- fused 4-cell streaming LSTM (R4 grid) + pipelined X-GEMM ----------------
// 240 WGs: cell0=wg[0,16) d=1; cell1=[16,48) d=2; cell2=[48,112) d=4; cell3=[112,240) d=8.
// All WGs of one ib share an XCD. RELAXED polls + one acquire fence per quantum (R4).
// NEW: X-GEMM for step j+1 computed at the END of step j into xacc[] (independent of h),
// so step j's h-GEMM chain starts from C=xacc (4-deep, not 6) and X-load latency is
// entirely off the loop-carried path.
struct FArgs {
  const _Float16* win;
  const _Float16* wihf[4];
  const _Float16* whhf[4];
  const float* biasp[4];
  _Float16* H[4];
  int* prog;
};

__device__ __forceinline__ void wait_prog(int* p, int need, int& fenced, int* obs_sh) {
  if (need <= fenced) return;  // uniform condition: no divergence hazard
  if (threadIdx.x == 0) {
    int v;
    while ((v = __hip_atomic_load(p, __ATOMIC_RELAXED, __HIP_MEMORY_SCOPE_AGENT)) < need)
      __builtin_amdgcn_s_sleep(16);
    *obs_sh = v;
  }
  __syncthreads();
  int v = *obs_sh;
  __builtin_amdgcn_fence(__ATOMIC_ACQUIRE, "agent");  // single buffer_inv
  fenced = v;
}

template <int KXB, bool POLL, bool REL>
__device__ __forceinline__ void floop(const _Float16* __restrict__ Xsrc,
                                      const _Float16* __restrict__ wihp,
                                      const _Float16* __restrict__ whhp,
                                      const float* __restrict__ bp, _Float16* __restrict__ Hout,
                                      int* progIn, int sprev, int* progOut, int d, int kd, int ib,
                                      _Float16 (*hbuf)[2048], int* obs_sh) {
  int tid = threadIdx.x;
  int wv = tid >> 6, lane = tid & 63, m = lane & 15, kq = lane >> 4;
  half8 wxf[4][KXB], whf[4][4];
#pragma unroll
  for (int g = 0; g < 4; ++g) {
#pragma unroll
    for (int kb = 0; kb < KXB; ++kb)
      wxf[g][kb] = *(const half8*)(wihp + ((((wv * 4 + g) * KXB + kb) * 64 + lane) * 8));
#pragma unroll
    for (int kb = 0; kb < 4; ++kb)
      whf[g][kb] = *(const half8*)(whhp + ((((wv * 4 + g) * 4 + kb) * 64 + lane) * 8));
  }
  float bg[4];
#pragma unroll
  for (int g = 0; g < 4; ++g) bg[g] = bp[(wv * 4 + g) * 16 + m];
  float cc[4] = {0.f, 0.f, 0.f, 0.f};
  int nsteps = (kW - kd + d - 1) / d;
  const int xstride = KXB * 32;
  int fenced = 0;
  if (POLL) wait_prog(progIn + (kd & ((1 << sprev) - 1)), (kd >> sprev) + 1, fenced, obs_sh);
  floatx4 xacc[4];
  {  // prologue: X pre-gates for step 0
    const _Float16* xrow = Xsrc + (size_t)(kd * kB + ib * 16 + m) * xstride + kq * 8;
    half8 hx[KXB];
#pragma unroll
    for (int kb = 0; kb < KXB; ++kb) hx[kb] = *(const half8*)(xrow + kb * 32);
#pragma unroll
    for (int g = 0; g < 4; ++g) {
      xacc[g] = (floatx4){bg[g], bg[g], bg[g], bg[g]};
#pragma unroll
      for (int kb = 0; kb < KXB; ++kb)
        xacc[g] = __builtin_amdgcn_mfma_f32_16x16x32_f16(hx[kb], wxf[g][kb], xacc[g], 0, 0, 0);
    }
  }
  for (int j = 0; j < nsteps; ++j) {
    int ph = j & 1;
    int wt = j * d + kd;
    int wtn = wt + d;
    bool havenext = (j + 1 < nsteps);
    if (POLL && havenext)  // confirm next tile before loading from it
      wait_prog(progIn + (wtn & ((1 << sprev) - 1)), (wtn >> sprev) + 1, fenced, obs_sh);
    half8 hx[KXB];
    if (havenext) {  // issue X loads for step j+1 (consumed at end of this step)
      const _Float16* xrow = Xsrc + (size_t)(wtn * kB + ib * 16 + m) * xstride + kq * 8;
#pragma unroll
      for (int kb = 0; kb < KXB; ++kb) hx[kb] = *(const half8*)(xrow + kb * 32);
    }
    // h-GEMM for step j, chained from C=xacc (critical path: ds_read + 4 MFMAs)
    floatx4 acc[4];
    if (j > 0) {
      half8 a[4];
#pragma unroll
      for (int kb = 0; kb < 4; ++kb) {
        int gran = (kb * 4 + kq) ^ m;
        a[kb] = *(const half8*)(&hbuf[ph ^ 1][m * 128 + gran * 8]);
      }
#pragma unroll
      for (int g = 0; g < 4; ++g) acc[g] = xacc[g];
#pragma unroll
      for (int kb = 0; kb < 4; ++kb)
#pragma unroll
        for (int g = 0; g < 4; ++g)
          acc[g] = __builtin_amdgcn_mfma_f32_16x16x32_f16(a[kb], whf[g][kb], acc[g], 0, 0, 0);
    } else {
#pragma unroll
      for (int g = 0; g < 4; ++g) acc[g] = xacc[g];
    }
    // gate math, 8 trans ops/h (g-gate prescaled by 2*log2e)
    _Float16 hv[4];
#pragma unroll
    for (int r = 0; r < 4; ++r) {
      float ea = FEXP2(-acc[0][r]);
      float ef = FEXP2(-acc[1][r]);
      float eb = FEXP2(-acc[2][r]);
      float eo = FEXP2(-acc[3][r]);
      float fv = FRCP(1.0f + ef);
      float it = (1.0f - eb) * FRCP((1.0f + ea) * (1.0f + eb));
      cc[r] = fv * cc[r] + it;
      float ed = FEXP2(cc[r] * (-2.0f * kLOG2E));
      hv[r] = (_Float16)((1.0f - ed) * FRCP((1.0f + eo) * (1.0f + ed)));
      int brow = kq * 4 + r;
      int hu = wv * 16 + m;
      int gran = (hu >> 3) ^ brow;
      hbuf[ph][brow * 128 + gran * 8 + (hu & 7)] = hv[r];
    }
    {  // Hout store (register-sourced; no LDS dependency -> before barrier, drains lazily)
      int hu = wv * 16 + m;
      size_t rb = (size_t)(wt * kB + ib * 16 + kq * 4);
#pragma unroll
      for (int r = 0; r < 4; ++r) Hout[(rb + r) * kH + hu] = hv[r];
    }
    if (havenext) {  // pipelined X-GEMM for step j+1 (independent MFMAs, fills matrix pipe)
#pragma unroll
      for (int g = 0; g < 4; ++g) {
        xacc[g] = (floatx4){bg[g], bg[g], bg[g], bg[g]};
#pragma unroll
        for (int kb = 0; kb < KXB; ++kb)
          xacc[g] = __builtin_amdgcn_mfma_f32_16x16x32_f16(hx[kb], wxf[g][kb], xacc[g], 0, 0, 0);
      }
    }
    LGKM_BARRIER();  // LDS-only: global loads/stores stay in flight
    if (REL && (((j & 7) == 7) || (j + 1 == nsteps))) {
      __syncthreads();  // full drain (vmcnt0): H stores visible before release
      if (tid == 0)
        __hip_atomic_store(progOut, j + 1, __ATOMIC_RELEASE, __HIP_MEMORY_SCOPE_AGENT);
    }
  }
}

__global__ __launch_bounds__(512) void k_fused(FArgs a) {
  __shared__ _Float16 hbuf[2][2048];
  __shared__ int obs_sh;
  int w = blockIdx.x;
  int cell, d, kd, ib;
  if (w < 16) {
    cell = 0; d = 1; kd = 0; ib = w;
  } else if (w < 48) {
    cell = 1; d = 2; kd = (w - 16) >> 4; ib = (w - 16) & 15;
  } else if (w < 112) {
    cell = 2; d = 4; kd = (w - 48) >> 4; ib = (w - 48) & 15;
  } else {
    cell = 3; d = 8; kd = (w - 112) >> 4; ib = (w - 112) & 15;
  }
  const _Float16* Xsrc = (cell == 0) ? a.win : a.H[cell - 1];
  _Float16* Hout = a.H[cell];
  int* progOut = a.prog + (cell * 16 + ib) * 4 + kd;
  int* progIn = (cell > 0) ? a.prog + ((cell - 1) * 16 + ib) * 4 : nullptr;
  int sprev = (cell == 2) ? 1 : ((cell == 3) ? 2 : 0);
  if (cell == 0)
    floop<2, false, true>(Xsrc, a.wihf[0], a.whhf[0], a.biasp[0], Hout, nullptr, 0, progOut, d,
                          kd, ib, hbuf, &obs_sh);
  else if (cell < 3)
    floop<4, true, true>(Xsrc, a.wihf[cell], a.whhf[cell], a.biasp[cell], Hout, progIn, sprev,
                         progOut, d, kd, ib, hbuf, &obs_sh);
  else
    floop<4, true, false>(Xsrc, a.wihf[3], a.whhf[3], a.biasp[3], Hout, progIn, sprev, progOut,
                          d, kd, ib, hbuf, &obs_sh);
}

// ---------------- tail: outputs 2, 4, 5 ----------------
__global__ void k_tail(const float* __restrict__ out3, const float* __restrict__ val,
                       const float* __restrict__ seas, const float* __restrict__ levs,
                       float* __restrict__ out2, float* __restrict__ out4,
                       float* __restrict__ out5) {
  int idx = blockIdx.x * 256 + threadIdx.x;
  int b = idx / kOUT, j = idx % kOUT;
  float s = seas[(kT + j) * kB + b];
  float L = levs[(kT - 1) * kB + b];
  float net = out3[(size_t)(kW - 1) * kB * kOUT + idx];
  float hp = net * s * L;
  out2[idx] = hp > 0.0f ? hp : 0.0f;
  float v = val[idx];
  out4[idx] = v;
  out5[idx] = v / s / L;
}

extern "C" void kernel_launch(void* const* d_in, const int* in_sizes, int n_in, void* d_out,
                              int out_size, void* d_ws, size_t ws_size, hipStream_t stream) {
  const float* train = (const float*)d_in[0];
  const float* val = (const float*)d_in[1];
  const float* levp = (const float*)d_in[3];
  const float* seasp = (const float*)d_in[4];
  const float* inits = (const float*)d_in[5];
  const float* w_ih[4] = {(const float*)d_in[6], (const float*)d_in[10], (const float*)d_in[14],
                          (const float*)d_in[18]};
  const float* w_hh[4] = {(const float*)d_in[7], (const float*)d_in[11], (const float*)d_in[15],
                          (const float*)d_in[19]};
  const float* b_ih[4] = {(const float*)d_in[8], (const float*)d_in[12], (const float*)d_in[16],
                          (const float*)d_in[20]};
  const float* b_hh[4] = {(const float*)d_in[9], (const float*)d_in[13], (const float*)d_in[17],
                          (const float*)d_in[21]};
  const float* nl_w = (const float*)d_in[22];
  const float* nl_b = (const float*)d_in[23];
  const float* sc_w = (const float*)d_in[24];
  const float* sc_b = (const float*)d_in[25];

  char* wsb = (char*)d_ws;
  size_t off = 0;
  auto alloc = [&](size_t bytes) -> void* {
    void* p = wsb + off;
    off = (off + bytes + 255) & ~(size_t)255;
    return p;
  };
  float* trainT = (float*)alloc((size_t)kT * kB * 4);
  float* seas = (float*)alloc((size_t)560 * kB * 4);
  float* levs = (float*)alloc((size_t)kT * kB * 4);
  _Float16* win = (_Float16*)alloc((size_t)kNB * 64 * 2);
  _Float16* Hc[4];
  for (int c = 0; c < 4; ++c) Hc[c] = (_Float16*)alloc((size_t)kNB * kH * 2);
  _Float16* U = (_Float16*)alloc((size_t)kNB * kH * 2);
  float* biasp[4];
  for (int c = 0; c < 4; ++c) biasp[c] = (float*)alloc(512 * 4);
  _Float16* wihf[4];
  wihf[0] = (_Float16*)alloc((size_t)32 * 2 * 512 * 2);
  for (int c = 1; c < 4; ++c) wihf[c] = (_Float16*)alloc((size_t)32 * 4 * 512 * 2);
  _Float16* whhf[4];
  for (int c = 0; c < 4; ++c) whhf[c] = (_Float16*)alloc((size_t)32 * 4 * 512 * 2);
  _Float16* nlf = (_Float16*)alloc((size_t)8 * 4 * 512 * 2);
  _Float16* scf = (_Float16*)alloc((size_t)3 * 4 * 512 * 2);
  int* prog = (int*)alloc(256 * 4);

  float* out0 = (float*)d_out;
  float* out1 = out0 + (size_t)kWO * kB * kOUT;
  float* out2 = out1 + (size_t)kWO * kB * kOUT;
  float* out3 = out2 + (size_t)kB * kOUT;
  float* out4 = out3 + (size_t)kW * kB * kOUT;
  float* out5 = out4 + (size_t)kB * kOUT;

  k_transpose<<<kT, kB, 0, stream>>>(train, trainT);
  k_es<<<1, kB, 0, stream>>>(trainT, levp, seasp, inits, seas, levs);
  k_win_in<<<kW, kB, 0, stream>>>(trainT, seas, levs, win);
  k_win_out<<<(kWO * kB * 12 + 255) / 256, 256, 0, stream>>>(trainT, seas, levs, out1);

  PrepArgs pa;
  for (int c = 0; c < 4; ++c) {
    pa.bih[c] = b_ih[c]; pa.bhh[c] = b_hh[c]; pa.biasp[c] = biasp[c];
    pa.wih[c] = w_ih[c]; pa.wihf[c] = wihf[c];
    pa.whh[c] = w_hh[c]; pa.whhf[c] = whhf[c];
  }
  pa.nlw = nl_w; pa.nlf = nlf; pa.scw = sc_w; pa.scf = scf;
  k_prep_all<<<dim3(256, 14), 256, 0, stream>>>(pa);
  k_zero_prog<<<1, 256, 0, stream>>>(prog);

  FArgs fa;
  fa.win = win;
  for (int c = 0; c < 4; ++c) {
    fa.wihf[c] = wihf[c]; fa.whhf[c] = whhf[c]; fa.biasp[c] = biasp[c]; fa.H[c] = Hc[c];
  }
  fa.prog = prog;
  void* kp[1] = {(void*)&fa};
  hipLaunchCooperativeKernel((void*)k_fused, dim3(240), dim3(512), kp, 0, stream);

  const int GG = kMBLK / 8;  // 930
  // nl: A = H3 + H1 (residual), tanh -> U
  k_gemm<8, 4, 1><<<GG, 512, 0, stream>>>(Hc[3], Hc[1], 128, nlf, nl_b, U, nullptr, nullptr);
  // sc: f32 out -> net_out_all (out3) + network_pred (out0)
  k_gemm<3, 4, 2><<<GG, 512, 0, stream>>>(U, nullptr, 128, scf, sc_b, nullptr, out3, out0);
  k_tail<<<48, 256, 0, stream>>>(out3, val, seas, levs, out2, out4, out5);
}

// Round 10
// 687.838 us; speedup vs baseline: 1.5377x; 1.0727x over previous
//
#include <hip/hip_runtime.h>
#include <cstdint>
#include <cstddef>

typedef _Float16 half8 __attribute__((ext_vector_type(8)));
typedef _Float16 half4 __attribute__((ext_vector_type(4)));
typedef float floatx4 __attribute__((ext_vector_type(4)));

namespace {
constexpr int kB = 256, kT = 512, kIN = 48, kOUT = 48, kSEAS = 24, kH = 128;
constexpr int kW = kT - kIN + 1;           // 465 windows
constexpr int kWO = kT - kOUT - kIN + 1;   // 417
constexpr int kNB = kW * kB;               // 119040 rows
constexpr int kMBLK = kNB / 16;            // 7440 row-blocks of 16
constexpr float kLOG2E = 1.44269504088896340736f;
}

#if __has_builtin(__builtin_amdgcn_exp2f)
#define FEXP2(x) __builtin_amdgcn_exp2f(x)
#else
#define FEXP2(x) exp2f(x)
#endif
#if __has_builtin(__builtin_amdgcn_rcpf)
#define FRCP(x) __builtin_amdgcn_rcpf(x)
#else
#define FRCP(x) (1.0f / (x))
#endif

__device__ __forceinline__ float fsig(float y) { return FRCP(1.0f + FEXP2(-y)); }
__device__ __forceinline__ float ftanh(float x) { return 2.0f * fsig(2.0f * kLOG2E * x) - 1.0f; }

// ---------------- transpose train (B,T) -> (T,B) ----------------
__global__ void k_transpose(const float* __restrict__ train, float* __restrict__ trainT) {
  int t = blockIdx.x, b = threadIdx.x;
  trainT[t * kB + b] = train[b * kT + t];
}

// ---------------- exponential smoothing scan, BLOCKED (lag-24 structure) ----------------
// Seasonality feedback has lag exactly kSEAS=24: a 24-step block has all st values
// available at entry (previous block's sn, carried in registers). Serial chain is only
// the 24-FMA lev recurrence; all rcps pipeline. Also emits ratio[t][b] = x_t/seas_t.
template <int N>
__device__ __forceinline__ void es_block(int k0, int b, float lev_sm, float omb_l,
                                         float seas_sm, float omb_s, float& lev,
                                         float (&stprev)[kSEAS],
                                         const float* __restrict__ trainT,
                                         float* __restrict__ seas, float* __restrict__ levs,
                                         float* __restrict__ ratio) {
  float x[N], q[N], lv[N];
#pragma unroll
  for (int jj = 0; jj < N; ++jj) x[jj] = trainT[(k0 + jj + 1) * kB + b];
#pragma unroll
  for (int jj = 0; jj < N; ++jj) q[jj] = x[jj] * FRCP(stprev[jj]);  // pipelined rcps
#pragma unroll
  for (int jj = 0; jj < N; ++jj) {  // the only serial chain: 1 fma + 1 mul per step
    lev = lev_sm * q[jj] + omb_l * lev;
    lv[jj] = lev;
  }
#pragma unroll
  for (int jj = 0; jj < N; ++jj) {
    float sn = seas_sm * (x[jj] * FRCP(lv[jj])) + omb_s * stprev[jj];
    stprev[jj] = sn;  // becomes st 24 steps later
    seas[(k0 + jj + kSEAS + 1) * kB + b] = sn;
    levs[(k0 + jj + 1) * kB + b] = lv[jj];
    ratio[(k0 + jj + 1) * kB + b] = q[jj];
  }
}

__global__ void k_es(const float* __restrict__ trainT, const float* __restrict__ levp,
                     const float* __restrict__ seasp, const float* __restrict__ inits,
                     float* __restrict__ seas, float* __restrict__ levs,
                     float* __restrict__ ratio) {
  int b = threadIdx.x;
  float lev_sm = fsig(levp[0] * kLOG2E);
  float seas_sm = fsig(seasp[0] * kLOG2E);
  float omb_l = 1.0f - lev_sm, omb_s = 1.0f - seas_sm;
  float stprev[kSEAS];
  float s00 = expf(inits[0]);
#pragma unroll
  for (int s = 0; s < kSEAS; ++s) {
    float v = expf(inits[s]);
    seas[s * kB + b] = v;
    if (s >= 1) stprev[s - 1] = v;  // st(k)=S[k+1] for k=0..22
  }
  stprev[kSEAS - 1] = s00;  // st(23)=S[24]=s00
  seas[kSEAS * kB + b] = s00;
  float lev = trainT[b] * FRCP(s00);
  levs[b] = lev;
  ratio[b] = lev;  // ratio[0] = trainT[0]/seas[0]
#pragma unroll 1
  for (int blk = 0; blk < 21; ++blk)  // 21*24 = 504 steps
    es_block<24>(blk * kSEAS, b, lev_sm, omb_l, seas_sm, omb_s, lev, stprev, trainT, seas,
                 levs, ratio);
  es_block<7>(504, b, lev_sm, omb_l, seas_sm, omb_s, lev, stprev, trainT, seas, levs,
              ratio);  // 504..510
  for (int j = 0; j < kOUT - kSEAS; ++j)
    seas[(kT + kSEAS + j) * kB + b] = seas[(kT + j) * kB + b];
}

// ---------------- window build: win_in (f16, padded K=64), from ratio ----------------
__global__ void k_win_in(const float* __restrict__ ratio, const float* __restrict__ levs,
                         _Float16* __restrict__ win) {
  int w = blockIdx.x;
  int tid = threadIdx.x;
#pragma unroll
  for (int i = 0; i < 16; ++i) {
    int o = i * 256 + tid;
    int b = o >> 3;
    int j0 = (o & 7) * 8;
    half8 h;
    if (j0 < kIN) {
      float rl = FRCP(levs[(kIN - 1 + w) * kB + b]);
#pragma unroll
      for (int jj = 0; jj < 8; ++jj) {
        int j = j0 + jj;
        float v = (j < kIN) ? ratio[(w + j) * kB + b] * rl : 0.0f;
        h[jj] = (_Float16)v;
      }
    } else {
#pragma unroll
      for (int jj = 0; jj < 8; ++jj) h[jj] = (_Float16)0.0f;
    }
    *(half8*)(win + ((size_t)(w * kB + b)) * 64 + j0) = h;
  }
}

// ---------------- window build: win_out == output 1 (fp32), from ratio ----------------
__global__ void k_win_out(const float* __restrict__ ratio, const float* __restrict__ levs,
                          float* __restrict__ out1) {
  int idx = blockIdx.x * 256 + threadIdx.x;
  if (idx >= kWO * kB * (kOUT / 4)) return;
  int row = idx / 12;
  int j0 = (idx - row * 12) * 4;
  int wo = row >> 8;
  int b = row & 255;
  float rl = FRCP(levs[(kIN - 1 + wo) * kB + b]);
  floatx4 v;
#pragma unroll
  for (int jj = 0; jj < 4; ++jj) v[jj] = ratio[(kIN + wo + j0 + jj) * kB + b] * rl;
  *(floatx4*)(out1 + (size_t)row * kOUT + j0) = v;
}

// ---------------- weight prep (single kernel, blockIdx.y = segment) ----------------
__device__ __forceinline__ void prep_bias_elem(const float* bih, const float* bhh, float* dst,
                                               int c) {
  int ct = c >> 4, n16 = c & 15, g = ct & 3, wv = ct >> 2;
  int row = g * 128 + wv * 16 + n16;
  float sc = (g == 2) ? 2.0f * kLOG2E : kLOG2E;
  dst[c] = (bih[row] + bhh[row]) * sc;
}

__device__ __forceinline__ void prep_frag_elem(const float* Wsrc, _Float16* dst, int KB, int Kreal,
                                               int srcld, int perm, int idx) {
  int jj = idx & 7;
  int lane = (idx >> 3) & 63;
  int kb = (idx >> 9) % KB;
  int ct = idx / (KB * 512);
  int n16 = lane & 15;
  int k = kb * 32 + ((lane >> 4) << 3) + jj;
  int row;
  float sc;
  if (perm) {
    int g = ct & 3, wv = ct >> 2;
    row = g * 128 + wv * 16 + n16;
    sc = (g == 2) ? 2.0f * kLOG2E : kLOG2E;
  } else {
    row = ct * 16 + n16;
    sc = 1.0f;
  }
  float v = (k < Kreal) ? Wsrc[row * srcld + k] * sc : 0.0f;
  dst[idx] = (_Float16)v;
}

struct PrepArgs {
  const float* bih[4];
  const float* bhh[4];
  float* biasp[4];
  const float* wih[4];
  _Float16* wihf[4];
  const float* whh[4];
  _Float16* whhf[4];
  const float* nlw;
  _Float16* nlf;
  const float* scw;
  _Float16* scf;
};

__global__ void k_prep_all(PrepArgs a) {
  int seg = blockIdx.y;
  int idx = blockIdx.x * 256 + threadIdx.x;
  if (seg < 4) {
    if (idx < 512) prep_bias_elem(a.bih[seg], a.bhh[seg], a.biasp[seg], idx);
  } else if (seg == 4) {
    if (idx < 32 * 2 * 512) prep_frag_elem(a.wih[0], a.wihf[0], 2, 48, 48, 1, idx);
  } else if (seg < 8) {
    int c = seg - 4;
    if (idx < 32 * 4 * 512) prep_frag_elem(a.wih[c], a.wihf[c], 4, 128, 128, 1, idx);
  } else if (seg < 12) {
    int c = seg - 8;
    if (idx < 32 * 4 * 512) prep_frag_elem(a.whh[c], a.whhf[c], 4, 128, 128, 1, idx);
  } else if (seg == 12) {
    if (idx < 8 * 4 * 512) prep_frag_elem(a.nlw, a.nlf, 4, 128, 128, 0, idx);
  } else {
    if (idx < 3 * 4 * 512) prep_frag_elem(a.scw, a.scf, 4, 128, 128, 0, idx);
  }
}

__global__ void k_zero_prog(int* prog) {
  prog[threadIdx.x] = 0;
}

// ---------------- generic MFMA GEMM (nl: MODE1, sc: MODE2) ----------------
template <int NT, int KB, int MODE>
__global__ __launch_bounds__(512) void k_gemm(const _Float16* __restrict__ A,
                                              const _Float16* __restrict__ A2, int Khalfs,
                                              const _Float16* __restrict__ Bfr,
                                              const float* __restrict__ bias,
                                              _Float16* __restrict__ outh,
                                              float* __restrict__ outf,
                                              float* __restrict__ outf2) {
  __shared__ _Float16 bsh[NT * KB * 512];
  int tid = threadIdx.x;
  {
    const uint4* src = (const uint4*)Bfr;
    uint4* dst = (uint4*)bsh;
    for (int i = tid; i < NT * KB * 64; i += 512) dst[i] = src[i];
  }
  __syncthreads();
  int wv = tid >> 6, lane = tid & 63;
  int mblk = blockIdx.x * 8 + wv;
  if (mblk >= kMBLK) return;
  int m = lane & 15, kq = lane >> 4;
  const _Float16* arow = A + (size_t)(mblk * 16 + m) * Khalfs + kq * 8;
  half8 af[KB];
#pragma unroll
  for (int kb = 0; kb < KB; ++kb) af[kb] = *(const half8*)(arow + kb * 32);
  if constexpr (MODE == 1) {
    const _Float16* arow2 = A2 + (size_t)(mblk * 16 + m) * Khalfs + kq * 8;
#pragma unroll
    for (int kb = 0; kb < KB; ++kb) {
      half8 a2 = *(const half8*)(arow2 + kb * 32);
      af[kb] += a2;
    }
  }
#pragma unroll
  for (int t0 = 0; t0 < NT; t0 += 2) {
    float b0 = bias[t0 * 16 + m];
    floatx4 acc0 = {b0, b0, b0, b0};
    floatx4 acc1 = {0.f, 0.f, 0.f, 0.f};
    if (t0 + 1 < NT) {
      float b1 = bias[(t0 + 1) * 16 + m];
      acc1 = (floatx4){b1, b1, b1, b1};
    }
#pragma unroll
    for (int kb = 0; kb < KB; ++kb) {
      half8 bf0 = *(const half8*)(&bsh[((t0 * KB + kb) * 64 + lane) * 8]);
      acc0 = __builtin_amdgcn_mfma_f32_16x16x32_f16(af[kb], bf0, acc0, 0, 0, 0);
      if (t0 + 1 < NT) {
        half8 bf1 = *(const half8*)(&bsh[(((t0 + 1) * KB + kb) * 64 + lane) * 8]);
        acc1 = __builtin_amdgcn_mfma_f32_16x16x32_f16(af[kb], bf1, acc1, 0, 0, 0);
      }
    }
    if constexpr (MODE == 1) {
#pragma unroll
      for (int r = 0; r < 4; ++r) {
        int row = mblk * 16 + kq * 4 + r;
        outh[(size_t)row * kH + t0 * 16 + m] = (_Float16)ftanh(acc0[r]);
        if (t0 + 1 < NT) outh[(size_t)row * kH + (t0 + 1) * 16 + m] = (_Float16)ftanh(acc1[r]);
      }
    } else {
#pragma unroll
      for (int r = 0; r < 4; ++r) {
        int row = mblk * 16 + kq * 4 + r;
        float v0 = acc0[r];
        outf[(size_t)row * kOUT + t0 * 16 + m] = v0;
        if (row < kWO * kB) outf2[(size_t)row * kOUT + t0 * 16 + m] = v0;
        if (t0 + 1 < NT) {
          float v1 = acc1[r];
          outf[(size_t)row * kOUT + (t0 + 1) * 16 + m] = v1;
          if (row < kWO * kB) outf2[(size_t)row * kOUT + (t0 + 1) * 16 + m] = v1;
        }
      }
    }
  }
}

// ---------------- fused 4-cell streaming LSTM (R4-exact: best measured 573 us) ----------------
// 240 WGs: cell0=wg[0,16) d=1; cell1=[16,48) d=2; cell2=[48,112) d=4; cell3=[112,240) d=8.
// All WGs of one ib share an XCD. RELAXED polls + one acquire fence per quantum.
struct FArgs {
  const _Float16* win;
  const _Float16* wihf[4];
  const _Float16* whhf[4];
  const float* biasp[4];
  _Float16* H[4];
  int* prog;
};

__device__ __forceinline__ void wait_prog(int* p, int need, int& fenced, int* obs_sh) {
  if (need <= fenced) return;  // uniform condition: no divergence hazard
  if (threadIdx.x == 0) {
    int v;
    while ((v = __hip_atomic_load(p, __ATOMIC_RELAXED, __HIP_MEMORY_SCOPE_AGENT)) < need)
      __builtin_amdgcn_s_sleep(16);
    *obs_sh = v;
  }
  __syncthreads();
  int v = *obs_sh;
  __builtin_amdgcn_fence(__ATOMIC_ACQUIRE, "agent");  // single buffer_inv
  fenced = v;
}

template <int KXB, bool POLL, bool REL>
__device__ __forceinline__ void floop(const _Float16* __restrict__ Xsrc,
                                      const _Float16* __restrict__ wihp,
                                      const _Float16* __restrict__ whhp,
                                      const float* __restrict__ bp, _Float16* __restrict__ Hout,
                                      int* progIn, int sprev, int* progOut, int d, int kd, int ib,
                                      _Float16 (*hbuf)[2048], int* obs_sh) {
  int tid = threadIdx.x;
  int wv = tid >> 6, lane = tid & 63, m = lane & 15, kq = lane >> 4;
  half8 wxf[4][KXB], whf[4][4];
#pragma unroll
  for (int g = 0; g < 4; ++g) {
#pragma unroll
    for (int kb = 0; kb < KXB; ++kb)
      wxf[g][kb] = *(const half8*)(wihp + ((((wv * 4 + g) * KXB + kb) * 64 + lane) * 8));
#pragma unroll
    for (int kb = 0; kb < 4; ++kb)
      whf[g][kb] = *(const half8*)(whhp + ((((wv * 4 + g) * 4 + kb) * 64 + lane) * 8));
  }
  float bg[4];
#pragma unroll
  for (int g = 0; g < 4; ++g) bg[g] = bp[(wv * 4 + g) * 16 + m];
  float cc[4] = {0.f, 0.f, 0.f, 0.f};
  int nsteps = (kW - kd + d - 1) / d;
  const int xstride = KXB * 32;
  int fenced = 0;
  if (POLL) wait_prog(progIn + (kd & ((1 << sprev) - 1)), (kd >> sprev) + 1, fenced, obs_sh);
  half8 hxc[KXB], hxn[KXB];
  {
    const _Float16* xrow = Xsrc + (size_t)(kd * kB + ib * 16 + m) * xstride + kq * 8;
#pragma unroll
    for (int kb = 0; kb < KXB; ++kb) hxc[kb] = *(const half8*)(xrow + kb * 32);
  }
  for (int j = 0; j < nsteps; ++j) {
    int ph = j & 1;
    int wtn = (j + 1) * d + kd;
    bool havenext = (j + 1 < nsteps);
    if (POLL && havenext)  // confirm next tile before prefetching it
      wait_prog(progIn + (wtn & ((1 << sprev) - 1)), (wtn >> sprev) + 1, fenced, obs_sh);
    floatx4 acc[4];
#pragma unroll
    for (int g = 0; g < 4; ++g) acc[g] = (floatx4){bg[g], bg[g], bg[g], bg[g]};
    if (havenext) {  // prefetch next step's X (consumed next iteration)
      const _Float16* xrow = Xsrc + (size_t)(wtn * kB + ib * 16 + m) * xstride + kq * 8;
#pragma unroll
      for (int kb = 0; kb < KXB; ++kb) hxn[kb] = *(const half8*)(xrow + kb * 32);
    }
#pragma unroll
    for (int kb = 0; kb < KXB; ++kb)
#pragma unroll
      for (int g = 0; g < 4; ++g)
        acc[g] = __builtin_amdgcn_mfma_f32_16x16x32_f16(hxc[kb], wxf[g][kb], acc[g], 0, 0, 0);
    if (j > 0) {
#pragma unroll
      for (int kb = 0; kb < 4; ++kb) {
        int gran = (kb * 4 + kq) ^ m;
        half8 a = *(const half8*)(&hbuf[ph ^ 1][m * 128 + gran * 8]);
#pragma unroll
        for (int g = 0; g < 4; ++g)
          acc[g] = __builtin_amdgcn_mfma_f32_16x16x32_f16(a, whf[g][kb], acc[g], 0, 0, 0);
      }
    }
    _Float16 hv[4];
#pragma unroll
    for (int r = 0; r < 4; ++r) {
      float iv = fsig(acc[0][r]);
      float fv = fsig(acc[1][r]);
      float g2 = fsig(acc[2][r]);
      float ov = fsig(acc[3][r]);
      cc[r] = fv * cc[r] + iv * (2.0f * g2 - 1.0f);
      float tc = 2.0f * fsig(cc[r] * (2.0f * kLOG2E)) - 1.0f;
      hv[r] = (_Float16)(ov * tc);
      int brow = kq * 4 + r;
      int hu = wv * 16 + m;
      int gran = (hu >> 3) ^ brow;
      hbuf[ph][brow * 128 + gran * 8 + (hu & 7)] = hv[r];
    }
    __syncthreads();
    {  // direct register->global store (drains at a later barrier)
      int hu = wv * 16 + m;
      size_t rb = (size_t)((j * d + kd) * kB + ib * 16 + kq * 4);
#pragma unroll
      for (int r = 0; r < 4; ++r) Hout[(rb + r) * kH + hu] = hv[r];
    }
    if (REL && (((j & 7) == 7) || (j + 1 == nsteps))) {
      __syncthreads();  // full drain (vmcnt0) so H stores are visible before release
      if (tid == 0)
        __hip_atomic_store(progOut, j + 1, __ATOMIC_RELEASE, __HIP_MEMORY_SCOPE_AGENT);
    }
#pragma unroll
    for (int kb = 0; kb < KXB; ++kb) hxc[kb] = hxn[kb];
  }
}

__global__ __launch_bounds__(512) void k_fused(FArgs a) {
  __shared__ _Float16 hbuf[2][2048];
  __shared__ int obs_sh;
  int w = blockIdx.x;
  int cell, d, kd, ib;
  if (w < 16) {
    cell = 0; d = 1; kd = 0; ib = w;
  } else if (w < 48) {
    cell = 1; d = 2; kd = (w - 16) >> 4; ib = (w - 16) & 15;
  } else if (w < 112) {
    cell = 2; d = 4; kd = (w - 48) >> 4; ib = (w - 48) & 15;
  } else {
    cell = 3; d = 8; kd = (w - 112) >> 4; ib = (w - 112) & 15;
  }
  const _Float16* Xsrc = (cell == 0) ? a.win : a.H[cell - 1];
  _Float16* Hout = a.H[cell];
  int* progOut = a.prog + (cell * 16 + ib) * 4 + kd;
  int* progIn = (cell > 0) ? a.prog + ((cell - 1) * 16 + ib) * 4 : nullptr;
  int sprev = (cell == 2) ? 1 : ((cell == 3) ? 2 : 0);
  if (cell == 0)
    floop<2, false, true>(Xsrc, a.wihf[0], a.whhf[0], a.biasp[0], Hout, nullptr, 0, progOut, d,
                          kd, ib, hbuf, &obs_sh);
  else if (cell < 3)
    floop<4, true, true>(Xsrc, a.wihf[cell], a.whhf[cell], a.biasp[cell], Hout, progIn, sprev,
                         progOut, d, kd, ib, hbuf, &obs_sh);
  else
    floop<4, true, false>(Xsrc, a.wihf[3], a.whhf[3], a.biasp[3], Hout, progIn, sprev, progOut,
                          d, kd, ib, hbuf, &obs_sh);
}

// ---------------- tail: outputs 2, 4, 5 ----------------
__global__ void k_tail(const float* __restrict__ out3, const float* __restrict__ val,
                       const float* __restrict__ seas, const float* __restrict__ levs,
                       float* __restrict__ out2, float* __restrict__ out4,
                       float* __restrict__ out5) {
  int idx = blockIdx.x * 256 + threadIdx.x;
  int b = idx / kOUT, j = idx % kOUT;
  float s = seas[(kT + j) * kB + b];
  float L = levs[(kT - 1) * kB + b];
  float net = out3[(size_t)(kW - 1) * kB * kOUT + idx];
  float hp = net * s * L;
  out2[idx] = hp > 0.0f ? hp : 0.0f;
  float v = val[idx];
  out4[idx] = v;
  out5[idx] = v / s / L;
}

extern "C" void kernel_launch(void* const* d_in, const int* in_sizes, int n_in, void* d_out,
                              int out_size, void* d_ws, size_t ws_size, hipStream_t stream) {
  const float* train = (const float*)d_in[0];
  const float* val = (const float*)d_in[1];
  const float* levp = (const float*)d_in[3];
  const float* seasp = (const float*)d_in[4];
  const float* inits = (const float*)d_in[5];
  const float* w_ih[4] = {(const float*)d_in[6], (const float*)d_in[10], (const float*)d_in[14],
                          (const float*)d_in[18]};
  const float* w_hh[4] = {(const float*)d_in[7], (const float*)d_in[11], (const float*)d_in[15],
                          (const float*)d_in[19]};
  const float* b_ih[4] = {(const float*)d_in[8], (const float*)d_in[12], (const float*)d_in[16],
                          (const float*)d_in[20]};
  const float* b_hh[4] = {(const float*)d_in[9], (const float*)d_in[13], (const float*)d_in[17],
                          (const float*)d_in[21]};
  const float* nl_w = (const float*)d_in[22];
  const float* nl_b = (const float*)d_in[23];
  const float* sc_w = (const float*)d_in[24];
  const float* sc_b = (const float*)d_in[25];

  char* wsb = (char*)d_ws;
  size_t off = 0;
  auto alloc = [&](size_t bytes) -> void* {
    void* p = wsb + off;
    off = (off + bytes + 255) & ~(size_t)255;
    return p;
  };
  float* trainT = (float*)alloc((size_t)kT * kB * 4);
  float* seas = (float*)alloc((size_t)560 * kB * 4);
  float* levs = (float*)alloc((size_t)kT * kB * 4);
  float* ratio = (float*)alloc((size_t)kT * kB * 4);
  _Float16* win = (_Float16*)alloc((size_t)kNB * 64 * 2);
  _Float16* Hc[4];
  for (int c = 0; c < 4; ++c) Hc[c] = (_Float16*)alloc((size_t)kNB * kH * 2);
  _Float16* U = (_Float16*)alloc((size_t)kNB * kH * 2);
  float* biasp[4];
  for (int c = 0; c < 4; ++c) biasp[c] = (float*)alloc(512 * 4);
  _Float16* wihf[4];
  wihf[0] = (_Float16*)alloc((size_t)32 * 2 * 512 * 2);
  for (int c = 1; c < 4; ++c) wihf[c] = (_Float16*)alloc((size_t)32 * 4 * 512 * 2);
  _Float16* whhf[4];
  for (int c = 0; c < 4; ++c) whhf[c] = (_Float16*)alloc((size_t)32 * 4 * 512 * 2);
  _Float16* nlf = (_Float16*)alloc((size_t)8 * 4 * 512 * 2);
  _Float16* scf = (_Float16*)alloc((size_t)3 * 4 * 512 * 2);
  int* prog = (int*)alloc(256 * 4);

  float* out0 = (float*)d_out;
  float* out1 = out0 + (size_t)kWO * kB * kOUT;
  float* out2 = out1 + (size_t)kWO * kB * kOUT;
  float* out3 = out2 + (size_t)kB * kOUT;
  float* out4 = out3 + (size_t)kW * kB * kOUT;
  float* out5 = out4 + (size_t)kB * kOUT;

  k_transpose<<<kT, kB, 0, stream>>>(train, trainT);
  k_es<<<1, kB, 0, stream>>>(trainT, levp, seasp, inits, seas, levs, ratio);
  k_win_in<<<kW, kB, 0, stream>>>(ratio, levs, win);
  k_win_out<<<(kWO * kB * 12 + 255) / 256, 256, 0, stream>>>(ratio, levs, out1);

  PrepArgs pa;
  for (int c = 0; c < 4; ++c) {
    pa.bih[c] = b_ih[c]; pa.bhh[c] = b_hh[c]; pa.biasp[c] = biasp[c];
    pa.wih[c] = w_ih[c]; pa.wihf[c] = wihf[c];
    pa.whh[c] = w_hh[c]; pa.whhf[c] = whhf[c];
  }
  pa.nlw = nl_w; pa.nlf = nlf; pa.scw = sc_w; pa.scf = scf;
  k_prep_all<<<dim3(256, 14), 256, 0, stream>>>(pa);
  k_zero_prog<<<1, 256, 0, stream>>>(prog);

  FArgs fa;
  fa.win = win;
  for (int c = 0; c < 4; ++c) {
    fa.wihf[c] = wihf[c]; fa.whhf[c] = whhf[c]; fa.biasp[c] = biasp[c]; fa.H[c] = Hc[c];
  }
  fa.prog = prog;
  void* kp[1] = {(void*)&fa};
  hipLaunchCooperativeKernel((void*)k_fused, dim3(240), dim3(512), kp, 0, stream);

  const int GG = kMBLK / 8;  // 930
  // nl: A = H3 + H1 (residual), tanh -> U
  k_gemm<8, 4, 1><<<GG, 512, 0, stream>>>(Hc[3], Hc[1], 128, nlf, nl_b, U, nullptr, nullptr);
  // sc: f32 out -> net_out_all (out3) + network_pred (out0)
  k_gemm<3, 4, 2><<<GG, 512, 0, stream>>>(U, nullptr, 128, scf, sc_b, nullptr, out3, out0);
  k_tail<<<48, 256, 0, stream>>>(out3, val, seas, levs, out2, out4, out5);
}